// Round 1
// baseline (239.845 us; speedup 1.0000x reference)
//
#include <hip/hip_runtime.h>
#include <math.h>

#define Y_ 1024
#define X_ 2048
#define YX_ (Y_*X_)
#define RAD_ 12
#define NT_ 25
#define APC_ 15

struct W25 { float w[NT_]; };

// ---------------------------------------------------------------------------
// Stage 1 Y-smooth of the 7 input channels:
//   z in [0,4]  -> y channels (m00,m01,m10,m11,s), plain
//   z in [5,6]  -> symmetrized v channels computed on the fly:
//       v_sym0(y,x) = 0.5*(v0(y,x) - v0(Y-1-y,x))
//       v_sym1(y,x) = 0.5*(v1(y,x) + v1(Y-1-y,x))
// Circular (wrap) boundary in Y. Each thread: one float4 column, 8 y-outputs.
// ---------------------------------------------------------------------------
__global__ __launch_bounds__(256) void ksmooth_y7(
    const float* __restrict__ yin, const float* __restrict__ vin,
    float* __restrict__ out, W25 W)
{
  const int z  = blockIdx.z;                       // 0..6 (block-uniform)
  const int y0 = blockIdx.y * 8;                   // 8 output rows per block
  const int xo = (blockIdx.x * 256 + threadIdx.x) * 4;  // float offset in row

  float4 acc[8];
#pragma unroll
  for (int j = 0; j < 8; ++j) acc[j] = make_float4(0.f, 0.f, 0.f, 0.f);

#pragma unroll
  for (int t = 0; t < 32; ++t) {
    int r = y0 - RAD_ + t;
    if (r < 0)    r += Y_;
    if (r >= Y_)  r -= Y_;
    float4 val;
    if (z < 5) {
      val = *(const float4*)(yin + z * YX_ + r * X_ + xo);
    } else {
      const int   c   = z - 5;
      const float sgn = (c == 0) ? -1.f : 1.f;
      float4 a = *(const float4*)(vin + c * YX_ + r * X_ + xo);
      float4 b = *(const float4*)(vin + c * YX_ + (Y_ - 1 - r) * X_ + xo);
      val.x = 0.5f * (a.x + sgn * b.x);
      val.y = 0.5f * (a.y + sgn * b.y);
      val.z = 0.5f * (a.z + sgn * b.z);
      val.w = 0.5f * (a.w + sgn * b.w);
    }
#pragma unroll
    for (int j = 0; j < 8; ++j) {
      const int k = t - j;                         // tap index, compile-time
      if (k >= 0 && k < NT_) {
        const float wk = W.w[k];
        acc[j].x += wk * val.x; acc[j].y += wk * val.y;
        acc[j].z += wk * val.z; acc[j].w += wk * val.w;
      }
    }
  }
#pragma unroll
  for (int j = 0; j < 8; ++j)
    *(float4*)(out + z * YX_ + (y0 + j) * X_ + xo) = acc[j];
}

// Plain Y-smooth (used for the 5-channel postprocess), circular in Y.
__global__ __launch_bounds__(256) void ksmooth_y(
    const float* __restrict__ in, float* __restrict__ out, W25 W)
{
  const int z  = blockIdx.z;
  const int y0 = blockIdx.y * 8;
  const int xo = (blockIdx.x * 256 + threadIdx.x) * 4;

  float4 acc[8];
#pragma unroll
  for (int j = 0; j < 8; ++j) acc[j] = make_float4(0.f, 0.f, 0.f, 0.f);

#pragma unroll
  for (int t = 0; t < 32; ++t) {
    int r = y0 - RAD_ + t;
    if (r < 0)    r += Y_;
    if (r >= Y_)  r -= Y_;
    float4 val = *(const float4*)(in + z * YX_ + r * X_ + xo);
#pragma unroll
    for (int j = 0; j < 8; ++j) {
      const int k = t - j;
      if (k >= 0 && k < NT_) {
        const float wk = W.w[k];
        acc[j].x += wk * val.x; acc[j].y += wk * val.y;
        acc[j].z += wk * val.z; acc[j].w += wk * val.w;
      }
    }
  }
#pragma unroll
  for (int j = 0; j < 8; ++j)
    *(float4*)(out + z * YX_ + (y0 + j) * X_ + xo) = acc[j];
}

// X-smooth with edge-replicate boundary. One float4 output per thread,
// window of 28 floats (7 aligned float4 loads in the interior).
__global__ __launch_bounds__(256) void ksmooth_x(
    const float* __restrict__ in, float* __restrict__ out, W25 W)
{
  const int z  = blockIdx.z;
  const int yy = blockIdx.y;
  const int x0 = (blockIdx.x * 256 + threadIdx.x) * 4;
  const float* row = in + z * YX_ + yy * X_;

  float buf[28];
  if (x0 >= RAD_ && x0 + 4 + RAD_ <= X_) {
#pragma unroll
    for (int i = 0; i < 7; ++i) {
      float4 t = *(const float4*)(row + x0 - RAD_ + 4 * i);
      buf[4*i+0] = t.x; buf[4*i+1] = t.y; buf[4*i+2] = t.z; buf[4*i+3] = t.w;
    }
  } else {
#pragma unroll
    for (int i = 0; i < 28; ++i) {
      int xx = x0 - RAD_ + i;
      xx = xx < 0 ? 0 : (xx > X_ - 1 ? X_ - 1 : xx);
      buf[i] = row[xx];
    }
  }
  float a0 = 0.f, a1 = 0.f, a2 = 0.f, a3 = 0.f;
#pragma unroll
  for (int t = 0; t < NT_; ++t) {
    const float wk = W.w[t];
    a0 += wk * buf[t + 0];
    a1 += wk * buf[t + 1];
    a2 += wk * buf[t + 2];
    a3 += wk * buf[t + 3];
  }
  *(float4*)(out + z * YX_ + yy * X_ + x0) = make_float4(a0, a1, a2, a3);
}

// ---------------------------------------------------------------------------
// Pointwise: central differences of the 7 smoothed fields (dy circular,
// dx edge-clamped), then the full algebra. Writes the 5 pre-smooth output
// channels with the AP-cut columns zeroed.
// Smoothed channel order: 0..3 = m00,m01,m10,m11 ; 4 = s ; 5 = v0 ; 6 = v1.
// ---------------------------------------------------------------------------
__global__ __launch_bounds__(256) void kpoint(
    const float* __restrict__ gs,    // smoothed, 7ch
    const float* __restrict__ yin,   // raw y, 5ch
    const float* __restrict__ vin,   // raw v, 2ch
    float* __restrict__ out)         // 5ch pre-smooth
{
  const int yy = blockIdx.y;
  const int x0 = (blockIdx.x * 256 + threadIdx.x) * 4;
  const int yu = (yy + 1) & (Y_ - 1);
  const int yd = (yy - 1 + Y_) & (Y_ - 1);

  float dYg[7][4], dXg[7][4];
#pragma unroll
  for (int c = 0; c < 7; ++c) {
    const float* base = gs + c * YX_;
    float4 cc = *(const float4*)(base + yy * X_ + x0);
    float4 uu = *(const float4*)(base + yu * X_ + x0);
    float4 dd = *(const float4*)(base + yd * X_ + x0);
    float L  = (x0 == 0)       ? cc.x : base[yy * X_ + x0 - 1];
    float Rr = (x0 + 4 >= X_)  ? cc.w : base[yy * X_ + x0 + 4];
    dYg[c][0] = 0.5f * (uu.x - dd.x);
    dYg[c][1] = 0.5f * (uu.y - dd.y);
    dYg[c][2] = 0.5f * (uu.z - dd.z);
    dYg[c][3] = 0.5f * (uu.w - dd.w);
    dXg[c][0] = 0.5f * (cc.y - L);
    dXg[c][1] = 0.5f * (cc.z - cc.x);
    dXg[c][2] = 0.5f * (cc.w - cc.y);
    dXg[c][3] = 0.5f * (Rr - cc.z);
  }

  // raw fields
  float rm[5][4];
#pragma unroll
  for (int zc = 0; zc < 5; ++zc) {
    float4 t = *(const float4*)(yin + zc * YX_ + yy * X_ + x0);
    rm[zc][0] = t.x; rm[zc][1] = t.y; rm[zc][2] = t.z; rm[zc][3] = t.w;
  }
  float vs0[4], vs1[4];
  {
    float4 a = *(const float4*)(vin + 0 * YX_ + yy * X_ + x0);
    float4 b = *(const float4*)(vin + 0 * YX_ + (Y_ - 1 - yy) * X_ + x0);
    vs0[0] = 0.5f * (a.x - b.x); vs0[1] = 0.5f * (a.y - b.y);
    vs0[2] = 0.5f * (a.z - b.z); vs0[3] = 0.5f * (a.w - b.w);
    float4 c = *(const float4*)(vin + 1 * YX_ + yy * X_ + x0);
    float4 d = *(const float4*)(vin + 1 * YX_ + (Y_ - 1 - yy) * X_ + x0);
    vs1[0] = 0.5f * (c.x + d.x); vs1[1] = 0.5f * (c.y + d.y);
    vs1[2] = 0.5f * (c.z + d.z); vs1[3] = 0.5f * (c.w + d.w);
  }

  float o[5][4];
#pragma unroll
  for (int j = 0; j < 4; ++j) {
    const float m00r = rm[0][j], m01r = rm[1][j], m10r = rm[2][j], m11r = rm[3][j];
    const float sr   = rm[4][j];
    const float v0   = vs0[j], v1 = vs1[j];

    // omega = O[0][1] = -0.5*(d v0/dx - d v1/dy)
    const float w_  = -0.5f * (dXg[5][j] - dYg[6][j]);
    const float trE = dYg[5][j] + dXg[6][j];
    const float trm = m00r + m11r;

    const float adv00 = v0 * dYg[0][j] + v1 * dXg[0][j];
    const float adv01 = v0 * dYg[1][j] + v1 * dXg[1][j];
    const float adv10 = v0 * dYg[2][j] + v1 * dXg[2][j];
    const float adv11 = v0 * dYg[3][j] + v1 * dXg[3][j];

    const float lhs00 = adv00 + w_ * (m10r + m01r);
    const float lhs01 = adv01 + w_ * (m11r - m00r);
    const float lhs10 = adv10 + w_ * (m11r - m00r);
    const float lhs11 = adv11 - w_ * (m01r + m10r);

    const float f  = -(0.11f - 0.099f * sr)
                   + (0.767f + 0.055f * sr) * trE
                   + (0.732f - 0.59f  * sr) * trm;
    const float cd = (0.069f - 0.048f * sr) * trm;

    const float sd = -(v0 * dYg[4][j] + v1 * dXg[4][j]);

    const int   xg   = x0 + j;
    const float mask = (xg < APC_ || xg >= X_ - APC_) ? 0.f : 1.f;
    o[0][j] = mask * (f * m00r + cd - lhs00);
    o[1][j] = mask * (f * m01r      - lhs01);
    o[2][j] = mask * (f * m10r      - lhs10);
    o[3][j] = mask * (f * m11r      - lhs11);
    o[4][j] = mask * sd;
  }
#pragma unroll
  for (int zc = 0; zc < 5; ++zc)
    *(float4*)(out + zc * YX_ + yy * X_ + x0) =
        make_float4(o[zc][0], o[zc][1], o[zc][2], o[zc][3]);
}

// ---------------------------------------------------------------------------
extern "C" void kernel_launch(void* const* d_in, const int* in_sizes, int n_in,
                              void* d_out, int out_size, void* d_ws, size_t ws_size,
                              hipStream_t stream)
{
  const float* yin = (const float*)d_in[0];   // (5, 1024, 2048) f32
  const float* vin = (const float*)d_in[1];   // (2, 1024, 2048) f32
  float* out = (float*)d_out;                 // (5, 1024, 2048) f32

  // ws layout: A = 7ch temp (later reused as 5ch pre-smooth),
  //            B = 7ch smoothed (later reused as 5ch post-Y temp).
  float* wsA = (float*)d_ws;
  float* wsB = wsA + 7 * (size_t)YX_;

  // Gaussian weights computed on host (exact, matches numpy f32 to ~1 ulp),
  // passed by value -> lands in kernarg constant space, all accesses unrolled.
  W25 W;
  double wd[NT_], s = 0.0;
  for (int i = 0; i < NT_; ++i) {
    double x = i - RAD_;
    wd[i] = exp(-0.5 * (x / 3.0) * (x / 3.0));
    s += wd[i];
  }
  for (int i = 0; i < NT_; ++i) W.w[i] = (float)(wd[i] / s);

  // 1) Y-smooth of 7 input channels (v symmetrized on the fly)
  ksmooth_y7<<<dim3(2, 128, 7), 256, 0, stream>>>(yin, vin, wsA, W);
  // 2) X-smooth -> smoothed fields
  ksmooth_x <<<dim3(2, 1024, 7), 256, 0, stream>>>(wsA, wsB, W);
  // 3) gradients + algebra + AP-cut -> 5 pre-smooth channels (reuse A)
  kpoint    <<<dim3(2, 1024, 1), 256, 0, stream>>>(wsB, yin, vin, wsA);
  // 4) postprocess Y-smooth (reuse B)
  ksmooth_y <<<dim3(2, 128, 5), 256, 0, stream>>>(wsA, wsB, W);
  // 5) postprocess X-smooth -> final output
  ksmooth_x <<<dim3(2, 1024, 5), 256, 0, stream>>>(wsB, out, W);
}